// Round 7
// baseline (155.758 us; speedup 1.0000x reference)
//
#include <hip/hip_runtime.h>
#include <math.h>

#define CC 1024
#define SS 16
#define DD 512
#define RR (CC*SS)
#define EPSV 1e-8f

typedef __attribute__((ext_vector_type(8))) short short8;
typedef __attribute__((ext_vector_type(4))) float f32x4;
typedef unsigned short ushort_t;

__device__ __forceinline__ unsigned short f2bf(float f) {
  unsigned u = __float_as_uint(f);
  u += 0x7fffu + ((u >> 16) & 1u);       // RNE
  return (unsigned short)(u >> 16);
}

__device__ __forceinline__ float softplusf(float v) {
  return (v > 20.f) ? v : log1pf(expf(v));
}

// ---------------- Kernel 1: per-class precompute ----------------
__global__ __launch_bounds__(256) void k_pre(
    const float* __restrict__ x, unsigned* __restrict__ mn,
    float* __restrict__ simpos, ushort_t* __restrict__ xn) {
  __shared__ float xs[SS * DD];
  __shared__ float sums[DD];
  __shared__ float red[4];
  __shared__ float snm;
  __shared__ float rinv[SS];
  const int j = blockIdx.x, tid = threadIdx.x;
  const float4* xj = (const float4*)(x + (size_t)j * SS * DD);
  float4* xs4 = (float4*)xs;
  for (int i = tid; i < SS * DD / 4; i += 256) xs4[i] = xj[i];
  __syncthreads();
  float m2 = 0.f;
  {
    const int d0 = tid * 2;   // 256 threads x 2 cols = 512
    float s0 = 0.f, s1 = 0.f;
#pragma unroll
    for (int i = 0; i < SS; ++i) {
      s0 += xs[i * DD + d0];
      s1 += xs[i * DD + d0 + 1];
    }
    sums[d0] = s0; sums[d0 + 1] = s1;
    float ma = s0 * (1.0f / SS), mb = s1 * (1.0f / SS);
    m2 = fmaf(ma, ma, mb * mb);
  }
#pragma unroll
  for (int off = 32; off > 0; off >>= 1) m2 += __shfl_xor(m2, off, 64);
  const int wid = tid >> 6, lane = tid & 63;
  if (lane == 0) red[wid] = m2;
  __syncthreads();
  if (tid == 0) snm = sqrtf(red[0] + red[1] + red[2] + red[3]);
  __syncthreads();
  const float inm = (1.0f / SS) / snm;
  {
    const int d0 = tid * 2;
    unsigned lo = f2bf(sums[d0] * inm);
    unsigned hi = f2bf(sums[d0 + 1] * inm);
    mn[((size_t)j * DD + d0) >> 1] = lo | (hi << 16);
  }
  for (int i = wid; i < SS; i += 4) {
    float nx2 = 0.f, dxs = 0.f, t2 = 0.f;
    for (int d = lane; d < DD; d += 64) {
      float xv = xs[i * DD + d];
      float sc = sums[d];
      nx2 = fmaf(xv, xv, nx2);
      dxs = fmaf(xv, sc, dxs);
      float tv = sc - xv;
      t2 = fmaf(tv, tv, t2);
    }
#pragma unroll
    for (int off = 32; off > 0; off >>= 1) {
      nx2 += __shfl_xor(nx2, off, 64);
      dxs += __shfl_xor(dxs, off, 64);
      t2  += __shfl_xor(t2,  off, 64);
    }
    if (lane == 0) {
      float nxv = sqrtf(nx2);
      float tn  = sqrtf(t2);
      float num = (dxs - nx2) * (1.0f / (SS - 1));
      float den = fmaxf(nxv * tn * (1.0f / (SS - 1)), EPSV);
      rinv[i] = 1.0f / nxv;
      simpos[j * SS + i] = num / den;
    }
  }
  __syncthreads();
  {
    uint2* dst = (uint2*)(xn + (size_t)j * SS * DD);
    for (int idx = tid; idx < SS * DD / 4; idx += 256) {
      const int e = idx * 4;                 // 4 elems, same row (DD=512)
      const float ri = rinv[e >> 9];
      unsigned a = f2bf(xs[e] * ri),     b2 = f2bf(xs[e + 1] * ri);
      unsigned c = f2bf(xs[e + 2] * ri), d2 = f2bf(xs[e + 3] * ri);
      dst[idx] = make_uint2(a | (b2 << 16), c | (d2 << 16));
    }
  }
}

// ---------------- Kernel 2: LDS-free MFMA GEMM, kc-outer ----------------
// grid = 512 blocks (128 rb x 4 cb) x 256 thr, ZERO LDS, no barriers.
// Wave = 32 rows x 256 cols. The RESIDENT state is the accumulator tile
// acc[16][2] (128 VGPRs — the allocator must keep accumulators live, unlike
// the R3/R6 attempts where loop-invariant A loads were demoted to re-fetch).
// Per kc: 2 A-slice loads + 16 independent B loads + 32 independent MFMAs.
__global__ __launch_bounds__(256, 2) void k_gemm(
    const ushort_t* __restrict__ xn, const ushort_t* __restrict__ mn,
    const float* __restrict__ simpos, const float* __restrict__ wptr,
    const float* __restrict__ bptr, float* __restrict__ ps) {
  const int tid = threadIdx.x;
  const int wid = tid >> 6, lane = tid & 63;
  const int cL = lane & 15, quad = lane >> 4;
  const int bid = blockIdx.x;
  const int rb = bid & 127, cb = bid >> 7;
  const int r0 = rb * 128 + wid * 32;
  const int cbase = cb * 256;

  f32x4 acc[16][2];
#pragma unroll
  for (int t = 0; t < 16; ++t) {
    acc[t][0] = (f32x4){0.f, 0.f, 0.f, 0.f};
    acc[t][1] = (f32x4){0.f, 0.f, 0.f, 0.f};
  }

  const ushort_t* arow0 = xn + (size_t)(r0 + cL) * DD + quad * 8;
  const ushort_t* arow1 = xn + (size_t)(r0 + 16 + cL) * DD + quad * 8;
  const ushort_t* bbase = mn + (size_t)(cbase + cL) * DD + quad * 8;

#pragma unroll 1
  for (int kc = 0; kc < 16; ++kc) {
    const short8 a0 = *(const short8*)(arow0 + kc * 32);
    const short8 a1 = *(const short8*)(arow1 + kc * 32);
#pragma unroll
    for (int t = 0; t < 16; ++t) {
      const short8 bfr = *(const short8*)(bbase + (size_t)t * 16 * DD + kc * 32);
      acc[t][0] = __builtin_amdgcn_mfma_f32_16x16x32_bf16(a0, bfr, acc[t][0], 0, 0, 0);
      acc[t][1] = __builtin_amdgcn_mfma_f32_16x16x32_bf16(a1, bfr, acc[t][1], 0, 0, 0);
    }
  }

  // epilogue: diagonal swap + exp-sum over this wave's 256 cols
  const float wp = softplusf(wptr[0]), bv = bptr[0];
  const int jw0 = r0 >> 4, jw1 = (r0 + 16) >> 4;
  float sp0[4], sp1[4], sacc0[4] = {0,0,0,0}, sacc1[4] = {0,0,0,0};
#pragma unroll
  for (int r = 0; r < 4; ++r) {
    sp0[r] = simpos[r0 + quad * 4 + r];
    sp1[r] = simpos[r0 + 16 + quad * 4 + r];
  }
#pragma unroll
  for (int t = 0; t < 16; ++t) {
    const int c = cbase + t * 16 + cL;
    const bool d0 = (c == jw0), d1 = (c == jw1);
#pragma unroll
    for (int r = 0; r < 4; ++r) {
      const float s0 = d0 ? sp0[r] : acc[t][0][r];
      const float s1 = d1 ? sp1[r] : acc[t][1][r];
      sacc0[r] += __expf(fmaf(wp, s0, bv));
      sacc1[r] += __expf(fmaf(wp, s1, bv));
    }
  }
#pragma unroll
  for (int r = 0; r < 4; ++r) {
    float v0 = sacc0[r], v1 = sacc1[r];
#pragma unroll
    for (int off = 1; off < 16; off <<= 1) {
      v0 += __shfl_xor(v0, off, 64);
      v1 += __shfl_xor(v1, off, 64);
    }
    if (cL == 0) {
      ps[(size_t)(r0 + quad * 4 + r) * 4 + cb] = v0;
      ps[(size_t)(r0 + 16 + quad * 4 + r) * 4 + cb] = v1;
    }
  }
}

// ---------------- Kernel 3: per-row loss + block reduce ----------------
__global__ __launch_bounds__(256) void k_combine(
    const float* __restrict__ ps, const float* __restrict__ simpos,
    const float* __restrict__ wptr, const float* __restrict__ bptr,
    float* __restrict__ p2) {
  __shared__ float red[4];
  const int tid = threadIdx.x;
  const int row = blockIdx.x * 256 + tid;
  const float wp = softplusf(wptr[0]), bv = bptr[0];
  const float4 s4 = *(const float4*)(ps + (size_t)row * 4);
  const float s = (s4.x + s4.y) + (s4.z + s4.w);
  float v = logf(s) - fmaf(wp, simpos[row], bv);
#pragma unroll
  for (int off = 32; off > 0; off >>= 1) v += __shfl_xor(v, off, 64);
  if ((tid & 63) == 0) red[tid >> 6] = v;
  __syncthreads();
  if (tid == 0) p2[blockIdx.x] = red[0] + red[1] + red[2] + red[3];
}

__global__ __launch_bounds__(64) void k_fin(const float* __restrict__ p2,
                                            float* __restrict__ out) {
  const int tid = threadIdx.x;
  float v = p2[tid];
#pragma unroll
  for (int off = 32; off > 0; off >>= 1) v += __shfl_xor(v, off, 64);
  if (tid == 0) out[0] = v * (1.0f / RR);
}

extern "C" void kernel_launch(void* const* d_in, const int* in_sizes, int n_in,
                              void* d_out, int out_size, void* d_ws, size_t ws_size,
                              hipStream_t stream) {
  const float* x = (const float*)d_in[0];
  const float* w = (const float*)d_in[1];
  const float* b = (const float*)d_in[2];
  float* out = (float*)d_out;

  char* p = (char*)d_ws;
  ushort_t* xn  = (ushort_t*)p;  p += (size_t)RR * DD * 2;   // 16 MB
  ushort_t* mn  = (ushort_t*)p;  p += (size_t)CC * DD * 2;   // 1 MB
  float* simpos = (float*)p;     p += (size_t)RR * 4;        // 64 KB
  float* ps     = (float*)p;     p += (size_t)RR * 4 * 4;    // 256 KB
  float* p2     = (float*)p;

  k_pre<<<CC, 256, 0, stream>>>(x, (unsigned*)mn, simpos, xn);
  k_gemm<<<512, 256, 0, stream>>>(xn, mn, simpos, w, b, ps);
  k_combine<<<RR / 256, 256, 0, stream>>>(ps, simpos, w, b, p2);
  k_fin<<<1, 64, 0, stream>>>(p2, out);
}